// Round 14
// baseline (511.176 us; speedup 1.0000x reference)
//
#include <hip/hip_runtime.h>

using f32x4  = __attribute__((ext_vector_type(4))) float;
using bf16x8 = __attribute__((ext_vector_type(8))) __bf16;

#define AS1(p) ((__attribute__((address_space(1))) void*)(p))
#define AS3(p) ((__attribute__((address_space(3))) void*)(p))

__device__ __forceinline__ unsigned short f2bf(float f) {
    unsigned u = __float_as_uint(f);
    unsigned r = u + 0x7FFFu + ((u >> 16) & 1u);
    return (unsigned short)(r >> 16);
}

__device__ __forceinline__ unsigned cvtpk(float lo, float hi) {
    unsigned r;
    asm("v_cvt_pk_bf16_f32 %0, %1, %2" : "=v"(r) : "v"(lo), "v"(hi));
    return r;
}

__device__ __forceinline__ f32x4 mfma16(bf16x8 a, bf16x8 b, f32x4 c) {
    return __builtin_amdgcn_mfma_f32_16x16x32_bf16(a, b, c, 0, 0, 0);
}

// ---------------- prep kernels ----------------

__global__ void k_cvt_hidden(const float* __restrict__ in, unsigned short* __restrict__ out, long n) {
    long i0 = ((long)blockIdx.x * 256 + threadIdx.x) * 8;
    long stride = (long)gridDim.x * 256 * 8;
    for (long i = i0; i < n; i += stride) {
        float4 a = *(const float4*)&in[i];
        float4 b = *(const float4*)&in[i + 4];
        uint4 v;
        v.x = cvtpk(a.x, a.y);
        v.y = cvtpk(a.z, a.w);
        v.z = cvtpk(b.x, b.y);
        v.w = cvtpk(b.z, b.w);
        *(uint4*)&out[i] = v;
    }
}

__global__ void k_prep_enc(const float* __restrict__ enc, const float* __restrict__ qual,
                           unsigned short* __restrict__ out) {
    long total = 2L * 1280 * 1280 / 4;
    long i0 = (long)blockIdx.x * 256 + threadIdx.x;
    long stride = (long)gridDim.x * 256;
    for (long i = i0; i < total; i += stride) {
        long e = i * 4;
        int g = (int)(e / (1280L * 1280));
        long rem = e - (long)g * 1280 * 1280;
        int m = (int)(rem / 1280);
        uint2 v = {0u, 0u};
        if (m < 1232) {
            const float* src = (g ? qual : enc) + rem;
            float4 a = *(const float4*)src;
            v.x = f2bf(a.x) | ((unsigned)f2bf(a.y) << 16);
            v.y = f2bf(a.z) | ((unsigned)f2bf(a.w) << 16);
        }
        *(uint2*)&out[e] = v;
    }
}

__global__ void k_prep_w(const float* __restrict__ Wq, const float* __restrict__ Wout,
                         const float* __restrict__ Wks, const float* __restrict__ Wvs,
                         const float* __restrict__ Wkq, const float* __restrict__ Wvq,
                         unsigned short* __restrict__ wq_bt, unsigned short* __restrict__ wout_bt,
                         unsigned short* __restrict__ wkv_bt) {
    const float scale = 0.11180339887498949f; // 80^-0.5
    long i0 = (long)blockIdx.x * 256 + threadIdx.x;
    long stride = (long)gridDim.x * 256;
    for (long i = i0; i < 4096000L; i += stride) {
        if (i < 409600) {
            int n = (int)(i / 640), k = (int)(i % 640);
            wq_bt[i] = f2bf(Wq[(size_t)k * 640 + n] * scale);
        } else if (i < 819200) {
            long j = i - 409600;
            int n = (int)(j / 640), k = (int)(j % 640);
            wout_bt[j] = f2bf(Wout[(size_t)k * 640 + n]);
        } else {
            long j = i - 819200;
            int g = (int)(j / (1280L * 1280));
            long r = j - (long)g * 1280 * 1280;
            int n = (int)(r / 1280), k = (int)(r % 1280);
            const float* Wk = g ? Wkq : Wks;
            const float* Wv = g ? Wvq : Wvs;
            float val = (n < 640) ? Wk[(size_t)k * 640 + n] : Wv[(size_t)k * 640 + (n - 640)];
            wkv_bt[j] = f2bf(val);
        }
    }
}

// K -> Kg2[2][16][8][80][80] (row l, col d); V -> Vt2[2][16][8][80][80] (row d, col l)
__global__ void k_scatter(const unsigned short* __restrict__ kv,
                          unsigned short* __restrict__ Kg2, unsigned short* __restrict__ Vt2) {
    const long per = 2L * 16 * 8 * 80 * 40;
    const long total = 2 * per;
    long i0 = (long)blockIdx.x * 256 + threadIdx.x;
    long stride = (long)gridDim.x * 256;
    for (long i = i0; i < total; i += stride) {
        int arr = (int)(i / per);
        long r = i - (long)arr * per;
        int c2 = (int)(r % 40); r /= 40;
        int row = (int)(r % 80); r /= 80;
        int h = (int)(r % 8); r /= 8;
        int b = (int)(r % 16); r /= 16;
        int g = (int)r;
        size_t dst_u = (((size_t)g * 16 + b) * 8 + h) * 3200 + row * 40 + c2;
        if (arr == 0) {
            unsigned val = 0;
            if (row < 77)
                val = *(const unsigned*)&kv[(size_t)g * 1638400 + ((size_t)b * 77 + row) * 1280 + h * 80 + 2 * c2];
            ((unsigned*)Kg2)[dst_u] = val;
        } else {
            int l0 = 2 * c2;
            unsigned v0 = 0, v1 = 0;
            if (l0 < 77)
                v0 = kv[(size_t)g * 1638400 + ((size_t)b * 77 + l0) * 1280 + 640 + h * 80 + row];
            if (l0 + 1 < 77)
                v1 = kv[(size_t)g * 1638400 + ((size_t)b * 77 + l0 + 1) * 1280 + 640 + h * 80 + row];
            ((unsigned*)Vt2)[dst_u] = v0 | (v1 << 16);
        }
    }
}

// ---------------- GEMM: BK=64, single-buffer 2-barrier, XOR-swizzled LDS ----------------

template <int OUT_F32, int SWZ>
__global__ __launch_bounds__(256) void gemm_bt(
    const unsigned short* __restrict__ A, const unsigned short* __restrict__ Bt,
    void* __restrict__ Cv, int K, int N, long zA, long zB, long zC)
{
    size_t m0; int n0;
    if (SWZ) {
        int i = blockIdx.x;
        int L = (i & 7) * 320 + (i >> 3);   // 2560 blocks, 8 XCDs, 320 per XCD
        n0 = (L % 5) * 128;
        m0 = (size_t)(L / 5) * 128;
    } else {
        m0 = (size_t)blockIdx.x * 128;
        n0 = blockIdx.y * 128;
    }
    const unsigned short* Ab = A + (size_t)blockIdx.z * zA;
    const unsigned short* Bb = Bt + (size_t)blockIdx.z * zB;
    __shared__ __attribute__((aligned(16))) unsigned short As[128 * 64];
    __shared__ __attribute__((aligned(16))) unsigned short Bs[128 * 64];
    const int tid = threadIdx.x, lane = tid & 63, wv = tid >> 6;
    const int wm = wv >> 1, wn = wv & 1;
    const int srow = lane >> 3;
    const int scol = ((lane & 7) ^ srow) * 8;
    f32x4 acc[4][4] = {};
    for (int k0 = 0; k0 < K; k0 += 64) {
        for (int c = wv; c < 16; c += 4) {
            __builtin_amdgcn_global_load_lds(AS1(Ab + (m0 + c * 8 + srow) * K + k0 + scol),
                                             AS3(&As[c * 512]), 16, 0, 0);
            __builtin_amdgcn_global_load_lds(AS1(Bb + ((size_t)(n0 + c * 8 + srow)) * K + k0 + scol),
                                             AS3(&Bs[c * 512]), 16, 0, 0);
        }
        asm volatile("s_waitcnt vmcnt(0)" ::: "memory");
        __syncthreads();
        const int q = lane >> 4, l15 = lane & 15;
#pragma unroll
        for (int kk = 0; kk < 2; ++kk) {
            bf16x8 a[4], b[4];
#pragma unroll
            for (int i = 0; i < 4; ++i) {
                int ra = wm * 64 + i * 16 + l15;
                int rb = wn * 64 + i * 16 + l15;
                a[i] = *(const bf16x8*)&As[ra * 64 + (((kk * 4 + q) ^ (ra & 7)) * 8)];
                b[i] = *(const bf16x8*)&Bs[rb * 64 + (((kk * 4 + q) ^ (rb & 7)) * 8)];
            }
#pragma unroll
            for (int mi = 0; mi < 4; ++mi)
#pragma unroll
                for (int ni = 0; ni < 4; ++ni)
                    acc[mi][ni] = mfma16(a[mi], b[ni], acc[mi][ni]);
        }
        __syncthreads();
    }
#pragma unroll
    for (int mi = 0; mi < 4; ++mi) {
#pragma unroll
        for (int ni = 0; ni < 4; ++ni) {
            size_t row = m0 + wm * 64 + mi * 16 + ((lane >> 4) * 4);
            int col = n0 + wn * 64 + ni * 16 + (lane & 15);
#pragma unroll
            for (int i = 0; i < 4; ++i) {
                float v = acc[mi][ni][i];
                if (OUT_F32)
                    ((float*)Cv + (size_t)blockIdx.z * zC)[(row + i) * N + col] = v;
                else
                    ((unsigned short*)Cv + (size_t)blockIdx.z * zC)[(row + i) * N + col] = f2bf(v);
            }
        }
    }
}

// ---------------- GEMM 64x128 tile (KV projection; 400 blocks), BK=32 ----------------
__global__ __launch_bounds__(256) void gemm_bt64(
    const unsigned short* __restrict__ A, const unsigned short* __restrict__ Bt,
    unsigned short* __restrict__ C, int K, int N, long zA, long zB, long zC)
{
    const size_t m0 = (size_t)blockIdx.x * 64;
    const int n0 = blockIdx.y * 128;
    const unsigned short* Ab = A + (size_t)blockIdx.z * zA;
    const unsigned short* Bb = Bt + (size_t)blockIdx.z * zB;
    __shared__ __attribute__((aligned(16))) unsigned short As[64 * 32];
    __shared__ __attribute__((aligned(16))) unsigned short Bs[128 * 32];
    const int tid = threadIdx.x, lane = tid & 63, wv = tid >> 6;
    const int srow = lane >> 2;
    const int scol = ((lane & 3) ^ (srow & 3)) * 8;
    f32x4 acc[4][2] = {};
    for (int k0 = 0; k0 < K; k0 += 32) {
        {
            int c = wv;
            __builtin_amdgcn_global_load_lds(AS1(Ab + (m0 + c * 16 + srow) * K + k0 + scol),
                                             AS3(&As[c * 512]), 16, 0, 0);
        }
        for (int c = wv; c < 8; c += 4)
            __builtin_amdgcn_global_load_lds(AS1(Bb + ((size_t)(n0 + c * 16 + srow)) * K + k0 + scol),
                                             AS3(&Bs[c * 512]), 16, 0, 0);
        asm volatile("s_waitcnt vmcnt(0)" ::: "memory");
        __syncthreads();
        const int q = lane >> 4, l15 = lane & 15;
        bf16x8 a[4], b[2];
#pragma unroll
        for (int i = 0; i < 4; ++i) {
            int ra = i * 16 + l15;
            a[i] = *(const bf16x8*)&As[ra * 32 + ((q ^ (ra & 3)) * 8)];
        }
#pragma unroll
        for (int j = 0; j < 2; ++j) {
            int rb = wv * 32 + j * 16 + l15;
            b[j] = *(const bf16x8*)&Bs[rb * 32 + ((q ^ (rb & 3)) * 8)];
        }
#pragma unroll
        for (int mi = 0; mi < 4; ++mi)
#pragma unroll
            for (int ni = 0; ni < 2; ++ni)
                acc[mi][ni] = mfma16(a[mi], b[ni], acc[mi][ni]);
        __syncthreads();
    }
#pragma unroll
    for (int mi = 0; mi < 4; ++mi) {
#pragma unroll
        for (int ni = 0; ni < 2; ++ni) {
            size_t row = m0 + mi * 16 + ((lane >> 4) * 4);
            int col = n0 + wv * 32 + ni * 16 + (lane & 15);
#pragma unroll
            for (int i = 0; i < 4; ++i)
                (C + (size_t)blockIdx.z * zC)[(row + i) * N + col] = f2bf(acc[mi][ni][i]);
        }
    }
}

// ---------------- fused dual attention: 4 rg/wave, staged K/V, direct epilogue ----------------
// grid (8 st, 8 h, 16 b) = 1024 blocks, 512 threads; wave owns 64 query rows (4 rg x 16).
// LDS = K/V only (51,200 B) -> 3 blocks/CU. Direct scalar stores (bounce measured equal).
__global__ __launch_bounds__(512, 6) void attn_kernel(
    const unsigned short* __restrict__ Q,    // [16][4096][640] bf16 (pre-scaled via Wq)
    const unsigned short* __restrict__ Kg2,  // [2][16][8][80][80]
    const unsigned short* __restrict__ Vt2,  // [2][16][8][80][80]
    const float* __restrict__ fw,            // [2]
    unsigned short* __restrict__ fused)      // [16][4096][640] bf16
{
    const int b = blockIdx.z, h = blockIdx.y;
    const int s0 = blockIdx.x * 512;
    __shared__ __attribute__((aligned(16))) unsigned short lds[4 * 6400]; // K0,K1,V0,V1
    const int tid = threadIdx.x, lane = tid & 63, wv = tid >> 6;
    const int l15 = lane & 15, q = lane >> 4;

    // ---- stage K/V (4 slabs x 800 chunks of 16B), LDS linear
    {
        const unsigned short* sK0 = Kg2 + (size_t)(b * 8 + h) * 6400;
        const unsigned short* sK1 = Kg2 + (size_t)((16 + b) * 8 + h) * 6400;
        const unsigned short* sV0 = Vt2 + (size_t)(b * 8 + h) * 6400;
        const unsigned short* sV1 = Vt2 + (size_t)((16 + b) * 8 + h) * 6400;
#pragma unroll
        for (int it = 0; it < 7; ++it) {
            int chunk = it * 512 + tid;
            if (chunk < 3200) {
                const unsigned short* src = sK0 + (size_t)chunk * 8;
                if (chunk >= 800)  src = sK1 + (size_t)(chunk - 800) * 8;
                if (chunk >= 1600) src = sV0 + (size_t)(chunk - 1600) * 8;
                if (chunk >= 2400) src = sV1 + (size_t)(chunk - 2400) * 8;
                __builtin_amdgcn_global_load_lds(AS1(src), AS3(&lds[(it * 512 + wv * 64) * 8]),
                                                 16, 0, 0);
            }
        }
    }

    // ---- Q fragments for all 4 row-groups (issued before the staging drain)
    bf16x8 aq[4][3];
#pragma unroll
    for (int rg = 0; rg < 4; ++rg) {
        const unsigned short* qrow = Q + ((size_t)b * 4096 + s0 + wv * 64 + rg * 16 + l15) * 640 + h * 80;
        aq[rg][0] = *(const bf16x8*)(qrow + q * 8);
        aq[rg][1] = *(const bf16x8*)(qrow + 32 + q * 8);
        if (q < 2) aq[rg][2] = *(const bf16x8*)(qrow + 64 + q * 8);
        else       aq[rg][2] = bf16x8{};
    }

    asm volatile("s_waitcnt vmcnt(0)" ::: "memory");
    __syncthreads();

    float f0 = fw[0], f1 = fw[1];
    float fm = fmaxf(f0, f1);
    float e0 = __expf(f0 - fm), e1 = __expf(f1 - fm);
    float w0 = e0 / (e0 + e1), w1 = e1 / (e0 + e1);

#pragma unroll
    for (int rg = 0; rg < 4; ++rg) {
        f32x4 o[5] = {};
#pragma unroll
        for (int g = 0; g < 2; ++g) {
            const unsigned short* Ks = &lds[g * 6400];
            const unsigned short* Vs = &lds[12800 + g * 6400];

            // ---- S^T = K * Q^T : lane holds query col s=l15, key rows l = 16t + 4q + i
            f32x4 s[5] = {};
            __builtin_amdgcn_s_setprio(1);
#pragma unroll
            for (int t = 0; t < 5; ++t)
#pragma unroll
                for (int kk = 0; kk < 3; ++kk) {
                    bf16x8 ak;
                    if (kk < 2 || q < 2) ak = *(const bf16x8*)&Ks[(t * 16 + l15) * 80 + kk * 32 + q * 8];
                    else                 ak = bf16x8{};
                    s[t] = mfma16(ak, aq[rg][kk], s[t]);
                }
            __builtin_amdgcn_s_setprio(0);

            // ---- no-max softmax over l (77 valid); scores are bounded (pre-scaled Q)
            float sum = 0.f;
#pragma unroll
            for (int t = 0; t < 4; ++t)
#pragma unroll
                for (int i = 0; i < 4; ++i) { s[t][i] = __expf(s[t][i]); sum += s[t][i]; }
#pragma unroll
            for (int i = 0; i < 4; ++i) {
                s[4][i] = (q * 4 + i < 13) ? __expf(s[4][i]) : 0.f;
                sum += s[4][i];
            }
            sum += __shfl_xor(sum, 16);
            sum += __shfl_xor(sum, 32);
            float rw = (g ? w1 : w0) / sum;   // fold fusion weight into P

            // ---- pack P quads (bf16)
            uint2 myq[5];
#pragma unroll
            for (int t = 0; t < 5; ++t) {
                myq[t].x = cvtpk(s[t][0] * rw, s[t][1] * rw);
                myq[t].y = cvtpk(s[t][2] * rw, s[t][3] * rw);
            }
            // ---- butterfly step 1 (xor16)
            uint4 A[6];
#pragma unroll
            for (int t = 0; t < 5; ++t) {
                unsigned px = __shfl_xor((int)myq[t].x, 16);
                unsigned py = __shfl_xor((int)myq[t].y, 16);
                if (q & 1) A[t] = uint4{px, py, myq[t].x, myq[t].y};
                else       A[t] = uint4{myq[t].x, myq[t].y, px, py};
            }
            A[5] = uint4{0u, 0u, 0u, 0u};

            // ---- PV with butterfly step 2 (xor32)
#pragma unroll
            for (int kk = 0; kk < 3; ++kk) {
                uint4 own = (q >> 1) ? A[2 * kk + 1] : A[2 * kk];
                uint4 snd = (q >> 1) ? A[2 * kk] : A[2 * kk + 1];
                uint4 rcv;
                rcv.x = __shfl_xor((int)snd.x, 32);
                rcv.y = __shfl_xor((int)snd.y, 32);
                rcv.z = __shfl_xor((int)snd.z, 32);
                rcv.w = __shfl_xor((int)snd.w, 32);
                uint4 fr = (q == 1 || q == 2) ? rcv : own;
                bf16x8 pa = __builtin_bit_cast(bf16x8, fr);
                __builtin_amdgcn_s_setprio(1);
#pragma unroll
                for (int t = 0; t < 5; ++t) {
                    bf16x8 bv;
                    if (kk < 2 || q < 2) bv = *(const bf16x8*)&Vs[(t * 16 + l15) * 80 + kk * 32 + q * 8];
                    else                 bv = bf16x8{};
                    o[t] = mfma16(pa, bv, o[t]);
                }
                __builtin_amdgcn_s_setprio(0);
            }
        }

        // ---- direct store epilogue (lane holds col d = 16t + l15, rows s = 4q + i)
        const size_t obase = ((size_t)b * 4096 + s0 + wv * 64 + rg * 16 + q * 4) * 640 + h * 80;
#pragma unroll
        for (int t = 0; t < 5; ++t)
#pragma unroll
            for (int i = 0; i < 4; ++i)
                fused[obase + (size_t)i * 640 + t * 16 + l15] = f2bf(o[t][i]);
    }
}

// ---------------- launcher ----------------

extern "C" void kernel_launch(void* const* d_in, const int* in_sizes, int n_in,
                              void* d_out, int out_size, void* d_ws, size_t ws_size,
                              hipStream_t stream) {
    const float* hidden = (const float*)d_in[0];
    const float* enc    = (const float*)d_in[1];
    const float* qual   = (const float*)d_in[2];
    const float* Wq     = (const float*)d_in[3];
    const float* Wks    = (const float*)d_in[4];
    const float* Wvs    = (const float*)d_in[5];
    const float* Wkq    = (const float*)d_in[6];
    const float* Wvq    = (const float*)d_in[7];
    const float* Wout   = (const float*)d_in[8];
    const float* fw     = (const float*)d_in[9];
    float* out = (float*)d_out;

    char* ws = (char*)d_ws;
    unsigned short* hid_bf  = (unsigned short*)(ws + 0);          // 83,886,080 B (reused as fused)
    unsigned short* Qb      = (unsigned short*)(ws + 83886080);   // 83,886,080 B
    unsigned short* encp    = (unsigned short*)(ws + 167772160);  // 6,553,600 B
    unsigned short* wq_bt   = (unsigned short*)(ws + 174325760);  // 819,200 B
    unsigned short* wout_bt = (unsigned short*)(ws + 175144960);  // 819,200 B
    unsigned short* wkv_bt  = (unsigned short*)(ws + 175964160);  // 6,553,600 B
    unsigned short* kvout   = (unsigned short*)(ws + 182517760);  // 6,553,600 B
    unsigned short* Kg2     = encp;    // overlays encp (dead after KV GEMM)
    unsigned short* Vt2     = wkv_bt;  // overlays wkv_bt (dead after KV GEMM)
    unsigned short* fused   = hid_bf;  // overlays hid_bf (dead after Q GEMM)

    k_cvt_hidden<<<dim3(2048), dim3(256), 0, stream>>>(hidden, hid_bf, 41943040L);
    k_prep_w<<<dim3(1024), dim3(256), 0, stream>>>(Wq, Wout, Wks, Wvs, Wkq, Wvq, wq_bt, wout_bt, wkv_bt);
    k_prep_enc<<<dim3(1024), dim3(256), 0, stream>>>(enc, qual, encp);
    gemm_bt64<<<dim3(20, 10, 2), dim3(256), 0, stream>>>(encp, wkv_bt, kvout, 1280, 1280,
                                                         1280L * 1280, 1280L * 1280, 1280L * 1280);
    k_scatter<<<dim3(1024), dim3(256), 0, stream>>>(kvout, Kg2, Vt2);
    gemm_bt<0, 1><<<dim3(2560), dim3(256), 0, stream>>>(hid_bf, wq_bt, (void*)Qb, 640, 640, 0L, 0L, 0L);
    attn_kernel<<<dim3(8, 8, 16), dim3(512), 0, stream>>>(Qb, Kg2, Vt2, fw, fused);
    gemm_bt<1, 1><<<dim3(2560), dim3(256), 0, stream>>>(fused, wout_bt, (void*)out, 640, 640, 0L, 0L, 0L);
}

// Round 15
// 402.871 us; speedup vs baseline: 1.2688x; 1.2688x over previous
//
#include <hip/hip_runtime.h>

using f32x4  = __attribute__((ext_vector_type(4))) float;
using bf16x8 = __attribute__((ext_vector_type(8))) __bf16;

#define AS1(p) ((__attribute__((address_space(1))) void*)(p))
#define AS3(p) ((__attribute__((address_space(3))) void*)(p))

__device__ __forceinline__ unsigned short f2bf(float f) {
    unsigned u = __float_as_uint(f);
    unsigned r = u + 0x7FFFu + ((u >> 16) & 1u);
    return (unsigned short)(r >> 16);
}

__device__ __forceinline__ unsigned cvtpk(float lo, float hi) {
    unsigned r;
    asm("v_cvt_pk_bf16_f32 %0, %1, %2" : "=v"(r) : "v"(lo), "v"(hi));
    return r;
}

__device__ __forceinline__ f32x4 mfma16(bf16x8 a, bf16x8 b, f32x4 c) {
    return __builtin_amdgcn_mfma_f32_16x16x32_bf16(a, b, c, 0, 0, 0);
}

// ---------------- prep kernels ----------------

__global__ void k_cvt_hidden(const float* __restrict__ in, unsigned short* __restrict__ out, long n) {
    long i0 = ((long)blockIdx.x * 256 + threadIdx.x) * 8;
    long stride = (long)gridDim.x * 256 * 8;
    for (long i = i0; i < n; i += stride) {
        float4 a = *(const float4*)&in[i];
        float4 b = *(const float4*)&in[i + 4];
        uint4 v;
        v.x = cvtpk(a.x, a.y);
        v.y = cvtpk(a.z, a.w);
        v.z = cvtpk(b.x, b.y);
        v.w = cvtpk(b.z, b.w);
        *(uint4*)&out[i] = v;
    }
}

// Merged prep: enc/qual -> encp[2][1280][1280] bf16 (zero-padded), plus all weight transposes.
__global__ void k_prep(const float* __restrict__ enc, const float* __restrict__ qual,
                       const float* __restrict__ Wq, const float* __restrict__ Wout,
                       const float* __restrict__ Wks, const float* __restrict__ Wvs,
                       const float* __restrict__ Wkq, const float* __restrict__ Wvq,
                       unsigned short* __restrict__ encp,
                       unsigned short* __restrict__ wq_bt, unsigned short* __restrict__ wout_bt,
                       unsigned short* __restrict__ wkv_bt) {
    const float scale = 0.11180339887498949f; // 80^-0.5
    const long total = 819200L + 4096000L;
    long i0 = (long)blockIdx.x * 256 + threadIdx.x;
    long stride = (long)gridDim.x * 256;
    for (long i = i0; i < total; i += stride) {
        if (i < 819200) {
            // enc path: item handles 4 consecutive bf16 (uint2)
            long e = i * 4;
            int g = (int)(e / (1280L * 1280));
            long rem = e - (long)g * 1280 * 1280;
            int m = (int)(rem / 1280);
            uint2 v = {0u, 0u};
            if (m < 1232) {
                const float* src = (g ? qual : enc) + rem;
                float4 a = *(const float4*)src;
                v.x = f2bf(a.x) | ((unsigned)f2bf(a.y) << 16);
                v.y = f2bf(a.z) | ((unsigned)f2bf(a.w) << 16);
            }
            *(uint2*)&encp[e] = v;
        } else {
            long w = i - 819200;
            if (w < 409600) {
                int n = (int)(w / 640), k = (int)(w % 640);
                wq_bt[w] = f2bf(Wq[(size_t)k * 640 + n] * scale);
            } else if (w < 819200) {
                long j = w - 409600;
                int n = (int)(j / 640), k = (int)(j % 640);
                wout_bt[j] = f2bf(Wout[(size_t)k * 640 + n]);
            } else {
                long j = w - 819200;
                int g = (int)(j / (1280L * 1280));
                long r = j - (long)g * 1280 * 1280;
                int n = (int)(r / 1280), k = (int)(r % 1280);
                const float* Wk = g ? Wkq : Wks;
                const float* Wv = g ? Wvq : Wvs;
                float val = (n < 640) ? Wk[(size_t)k * 640 + n] : Wv[(size_t)k * 640 + (n - 640)];
                wkv_bt[j] = f2bf(val);
            }
        }
    }
}

// ---------------- GEMM: BK=64, single-buffer 2-barrier, XOR-swizzled LDS ----------------

template <int OUT_F32, int SWZ>
__global__ __launch_bounds__(256) void gemm_bt(
    const unsigned short* __restrict__ A, const unsigned short* __restrict__ Bt,
    void* __restrict__ Cv, int K, int N, long zA, long zB, long zC)
{
    size_t m0; int n0;
    if (SWZ) {
        int i = blockIdx.x;
        int L = (i & 7) * 320 + (i >> 3);   // 2560 blocks, 8 XCDs, 320 per XCD
        n0 = (L % 5) * 128;
        m0 = (size_t)(L / 5) * 128;
    } else {
        m0 = (size_t)blockIdx.x * 128;
        n0 = blockIdx.y * 128;
    }
    const unsigned short* Ab = A + (size_t)blockIdx.z * zA;
    const unsigned short* Bb = Bt + (size_t)blockIdx.z * zB;
    __shared__ __attribute__((aligned(16))) unsigned short As[128 * 64];
    __shared__ __attribute__((aligned(16))) unsigned short Bs[128 * 64];
    const int tid = threadIdx.x, lane = tid & 63, wv = tid >> 6;
    const int wm = wv >> 1, wn = wv & 1;
    const int srow = lane >> 3;
    const int scol = ((lane & 7) ^ srow) * 8;
    f32x4 acc[4][4] = {};
    for (int k0 = 0; k0 < K; k0 += 64) {
        for (int c = wv; c < 16; c += 4) {
            __builtin_amdgcn_global_load_lds(AS1(Ab + (m0 + c * 8 + srow) * K + k0 + scol),
                                             AS3(&As[c * 512]), 16, 0, 0);
            __builtin_amdgcn_global_load_lds(AS1(Bb + ((size_t)(n0 + c * 8 + srow)) * K + k0 + scol),
                                             AS3(&Bs[c * 512]), 16, 0, 0);
        }
        asm volatile("s_waitcnt vmcnt(0)" ::: "memory");
        __syncthreads();
        const int q = lane >> 4, l15 = lane & 15;
#pragma unroll
        for (int kk = 0; kk < 2; ++kk) {
            bf16x8 a[4], b[4];
#pragma unroll
            for (int i = 0; i < 4; ++i) {
                int ra = wm * 64 + i * 16 + l15;
                int rb = wn * 64 + i * 16 + l15;
                a[i] = *(const bf16x8*)&As[ra * 64 + (((kk * 4 + q) ^ (ra & 7)) * 8)];
                b[i] = *(const bf16x8*)&Bs[rb * 64 + (((kk * 4 + q) ^ (rb & 7)) * 8)];
            }
#pragma unroll
            for (int mi = 0; mi < 4; ++mi)
#pragma unroll
                for (int ni = 0; ni < 4; ++ni)
                    acc[mi][ni] = mfma16(a[mi], b[ni], acc[mi][ni]);
        }
        __syncthreads();
    }
#pragma unroll
    for (int mi = 0; mi < 4; ++mi) {
#pragma unroll
        for (int ni = 0; ni < 4; ++ni) {
            size_t row = m0 + wm * 64 + mi * 16 + ((lane >> 4) * 4);
            int col = n0 + wn * 64 + ni * 16 + (lane & 15);
#pragma unroll
            for (int i = 0; i < 4; ++i) {
                float v = acc[mi][ni][i];
                if (OUT_F32)
                    ((float*)Cv + (size_t)blockIdx.z * zC)[(row + i) * N + col] = v;
                else
                    ((unsigned short*)Cv + (size_t)blockIdx.z * zC)[(row + i) * N + col] = f2bf(v);
            }
        }
    }
}

// ---------------- KV GEMM 64x128 with fused scatter epilogue ----------------
// C element (g, row, col): row = b*77+l (rows >=1232 discarded), col<640 -> K[g][b][h][l][d],
// col>=640 -> Vt[g][b][h][d][l].  Kg2/Vt2 pre-zeroed (padding l>=77 stays 0).
__global__ __launch_bounds__(256) void gemm_kv(
    const unsigned short* __restrict__ A, const unsigned short* __restrict__ Bt,
    unsigned short* __restrict__ Kg2, unsigned short* __restrict__ Vt2)
{
    const size_t m0 = (size_t)blockIdx.x * 64;
    const int n0 = blockIdx.y * 128;
    const int g = blockIdx.z;
    const unsigned short* Ab = A + (size_t)g * 1638400;
    const unsigned short* Bb = Bt + (size_t)g * 1638400;
    __shared__ __attribute__((aligned(16))) unsigned short As[64 * 32];
    __shared__ __attribute__((aligned(16))) unsigned short Bs[128 * 32];
    const int tid = threadIdx.x, lane = tid & 63, wv = tid >> 6;
    const int srow = lane >> 2;
    const int scol = ((lane & 3) ^ (srow & 3)) * 8;
    f32x4 acc[4][2] = {};
    for (int k0 = 0; k0 < 1280; k0 += 32) {
        {
            int c = wv;
            __builtin_amdgcn_global_load_lds(AS1(Ab + (m0 + c * 16 + srow) * 1280 + k0 + scol),
                                             AS3(&As[c * 512]), 16, 0, 0);
        }
        for (int c = wv; c < 8; c += 4)
            __builtin_amdgcn_global_load_lds(AS1(Bb + ((size_t)(n0 + c * 16 + srow)) * 1280 + k0 + scol),
                                             AS3(&Bs[c * 512]), 16, 0, 0);
        asm volatile("s_waitcnt vmcnt(0)" ::: "memory");
        __syncthreads();
        const int q = lane >> 4, l15 = lane & 15;
        bf16x8 a[4], b[2];
#pragma unroll
        for (int i = 0; i < 4; ++i) {
            int ra = i * 16 + l15;
            a[i] = *(const bf16x8*)&As[ra * 32 + ((q ^ (ra & 3)) * 8)];
        }
#pragma unroll
        for (int j = 0; j < 2; ++j) {
            int rb = wv * 32 + j * 16 + l15;
            b[j] = *(const bf16x8*)&Bs[rb * 32 + ((q ^ (rb & 3)) * 8)];
        }
#pragma unroll
        for (int mi = 0; mi < 4; ++mi)
#pragma unroll
            for (int ni = 0; ni < 2; ++ni)
                acc[mi][ni] = mfma16(a[mi], b[ni], acc[mi][ni]);
        __syncthreads();
    }
    // fused scatter epilogue
#pragma unroll
    for (int mi = 0; mi < 4; ++mi) {
#pragma unroll
        for (int ni = 0; ni < 2; ++ni) {
            int col = n0 + wv * 32 + ni * 16 + (lane & 15);
#pragma unroll
            for (int i = 0; i < 4; ++i) {
                int row = (int)m0 + mi * 16 + ((lane >> 4) * 4) + i;
                if (row < 1232) {
                    int b = row / 77, l = row - b * 77;
                    unsigned short val = f2bf(acc[mi][ni][i]);
                    if (col < 640) {
                        int h = col / 80, d = col - h * 80;
                        Kg2[(((size_t)g * 16 + b) * 8 + h) * 6400 + l * 80 + d] = val;
                    } else {
                        int c2 = col - 640;
                        int h = c2 / 80, d = c2 - h * 80;
                        Vt2[(((size_t)g * 16 + b) * 8 + h) * 6400 + d * 80 + l] = val;
                    }
                }
            }
        }
    }
}

// ---------------- fused dual attention: 4 row-groups/wave, staged K/V, bounce epilogue ----------------
// grid (8 st, 8 h, 16 b) = 1024 blocks, 512 threads. Each wave: 64 query rows (4 rg x 16).
// No-max softmax; setprio around MFMA clusters; per-wave LDS bounce -> 16B stores (R12 config).
__global__ __launch_bounds__(512, 4) void attn_kernel(
    const unsigned short* __restrict__ Q,    // [16][4096][640] bf16 (pre-scaled via Wq)
    const unsigned short* __restrict__ Kg2,  // [2][16][8][80][80]
    const unsigned short* __restrict__ Vt2,  // [2][16][8][80][80]
    const float* __restrict__ fw,            // [2]
    unsigned short* __restrict__ fused)      // [16][4096][640] bf16
{
    const int b = blockIdx.z, h = blockIdx.y;
    const int s0 = blockIdx.x * 512;
    __shared__ __attribute__((aligned(16))) unsigned short lds[25600 + 8 * 1408];
    const int tid = threadIdx.x, lane = tid & 63, wv = tid >> 6;
    const int l15 = lane & 15, q = lane >> 4;

    // ---- stage K/V (4 slabs x 800 chunks of 16B), LDS linear
    {
        const unsigned short* sK0 = Kg2 + (size_t)(b * 8 + h) * 6400;
        const unsigned short* sK1 = Kg2 + (size_t)((16 + b) * 8 + h) * 6400;
        const unsigned short* sV0 = Vt2 + (size_t)(b * 8 + h) * 6400;
        const unsigned short* sV1 = Vt2 + (size_t)((16 + b) * 8 + h) * 6400;
#pragma unroll
        for (int it = 0; it < 7; ++it) {
            int chunk = it * 512 + tid;
            if (chunk < 3200) {
                const unsigned short* src = sK0 + (size_t)chunk * 8;
                if (chunk >= 800)  src = sK1 + (size_t)(chunk - 800) * 8;
                if (chunk >= 1600) src = sV0 + (size_t)(chunk - 1600) * 8;
                if (chunk >= 2400) src = sV1 + (size_t)(chunk - 2400) * 8;
                __builtin_amdgcn_global_load_lds(AS1(src), AS3(&lds[(it * 512 + wv * 64) * 8]),
                                                 16, 0, 0);
            }
        }
    }

    // ---- Q fragments for all 4 row-groups (issued before the staging drain)
    bf16x8 aq[4][3];
#pragma unroll
    for (int rg = 0; rg < 4; ++rg) {
        const unsigned short* qrow = Q + ((size_t)b * 4096 + s0 + wv * 64 + rg * 16 + l15) * 640 + h * 80;
        aq[rg][0] = *(const bf16x8*)(qrow + q * 8);
        aq[rg][1] = *(const bf16x8*)(qrow + 32 + q * 8);
        if (q < 2) aq[rg][2] = *(const bf16x8*)(qrow + 64 + q * 8);
        else       aq[rg][2] = bf16x8{};
    }

    asm volatile("s_waitcnt vmcnt(0)" ::: "memory");
    __syncthreads();

    float f0 = fw[0], f1 = fw[1];
    float fm = fmaxf(f0, f1);
    float e0 = __expf(f0 - fm), e1 = __expf(f1 - fm);
    float w0 = e0 / (e0 + e1), w1 = e1 / (e0 + e1);

    unsigned short* obuf = &lds[25600 + wv * 1408];   // per-wave [16][88]

#pragma unroll
    for (int rg = 0; rg < 4; ++rg) {
        f32x4 o[5] = {};
#pragma unroll
        for (int g = 0; g < 2; ++g) {
            const unsigned short* Ks = &lds[g * 6400];
            const unsigned short* Vs = &lds[12800 + g * 6400];

            // ---- S^T = K * Q^T : lane holds query col s=l15, key rows l = 16t + 4q + i
            f32x4 s[5] = {};
            __builtin_amdgcn_s_setprio(1);
#pragma unroll
            for (int t = 0; t < 5; ++t)
#pragma unroll
                for (int kk = 0; kk < 3; ++kk) {
                    bf16x8 ak;
                    if (kk < 2 || q < 2) ak = *(const bf16x8*)&Ks[(t * 16 + l15) * 80 + kk * 32 + q * 8];
                    else                 ak = bf16x8{};
                    s[t] = mfma16(ak, aq[rg][kk], s[t]);
                }
            __builtin_amdgcn_s_setprio(0);

            // ---- no-max softmax over l (77 valid); scores are bounded (pre-scaled Q)
            float sum = 0.f;
#pragma unroll
            for (int t = 0; t < 4; ++t)
#pragma unroll
                for (int i = 0; i < 4; ++i) { s[t][i] = __expf(s[t][i]); sum += s[t][i]; }
#pragma unroll
            for (int i = 0; i < 4; ++i) {
                s[4][i] = (q * 4 + i < 13) ? __expf(s[4][i]) : 0.f;
                sum += s[4][i];
            }
            sum += __shfl_xor(sum, 16);
            sum += __shfl_xor(sum, 32);
            float rw = (g ? w1 : w0) / sum;   // fold fusion weight into P

            // ---- pack P quads (bf16)
            uint2 myq[5];
#pragma unroll
            for (int t = 0; t < 5; ++t) {
                myq[t].x = cvtpk(s[t][0] * rw, s[t][1] * rw);
                myq[t].y = cvtpk(s[t][2] * rw, s[t][3] * rw);
            }
            // ---- butterfly step 1 (xor16)
            uint4 A[6];
#pragma unroll
            for (int t = 0; t < 5; ++t) {
                unsigned px = __shfl_xor((int)myq[t].x, 16);
                unsigned py = __shfl_xor((int)myq[t].y, 16);
                if (q & 1) A[t] = uint4{px, py, myq[t].x, myq[t].y};
                else       A[t] = uint4{myq[t].x, myq[t].y, px, py};
            }
            A[5] = uint4{0u, 0u, 0u, 0u};

            // ---- PV with butterfly step 2 (xor32)
#pragma unroll
            for (int kk = 0; kk < 3; ++kk) {
                uint4 own = (q >> 1) ? A[2 * kk + 1] : A[2 * kk];
                uint4 snd = (q >> 1) ? A[2 * kk] : A[2 * kk + 1];
                uint4 rcv;
                rcv.x = __shfl_xor((int)snd.x, 32);
                rcv.y = __shfl_xor((int)snd.y, 32);
                rcv.z = __shfl_xor((int)snd.z, 32);
                rcv.w = __shfl_xor((int)snd.w, 32);
                uint4 fr = (q == 1 || q == 2) ? rcv : own;
                bf16x8 pa = __builtin_bit_cast(bf16x8, fr);
                __builtin_amdgcn_s_setprio(1);
#pragma unroll
                for (int t = 0; t < 5; ++t) {
                    bf16x8 bv;
                    if (kk < 2 || q < 2) bv = *(const bf16x8*)&Vs[(t * 16 + l15) * 80 + kk * 32 + q * 8];
                    else                 bv = bf16x8{};
                    o[t] = mfma16(pa, bv, o[t]);
                }
                __builtin_amdgcn_s_setprio(0);
            }
        }

        // ---- per-rg epilogue: wave-local LDS bounce -> coalesced 16B stores
#pragma unroll
        for (int t = 0; t < 5; ++t)
#pragma unroll
            for (int i = 0; i < 4; ++i)
                obuf[(q * 4 + i) * 88 + t * 16 + l15] = f2bf(o[t][i]);
        asm volatile("s_waitcnt lgkmcnt(0)" ::: "memory");   // wave-local only
        const size_t gbase = ((size_t)b * 4096 + s0 + wv * 64 + rg * 16) * 640 + h * 80;
#pragma unroll
        for (int it = 0; it < 3; ++it) {
            int c = it * 64 + lane;
            if (c < 160) {
                int r = c / 10, c10 = c % 10;
                *(uint4*)(fused + gbase + (size_t)r * 640 + c10 * 8) = *(const uint4*)&obuf[r * 88 + c10 * 8];
            }
        }
    }
}

// ---------------- launcher ----------------

extern "C" void kernel_launch(void* const* d_in, const int* in_sizes, int n_in,
                              void* d_out, int out_size, void* d_ws, size_t ws_size,
                              hipStream_t stream) {
    const float* hidden = (const float*)d_in[0];
    const float* enc    = (const float*)d_in[1];
    const float* qual   = (const float*)d_in[2];
    const float* Wq     = (const float*)d_in[3];
    const float* Wks    = (const float*)d_in[4];
    const float* Wvs    = (const float*)d_in[5];
    const float* Wkq    = (const float*)d_in[6];
    const float* Wvq    = (const float*)d_in[7];
    const float* Wout   = (const float*)d_in[8];
    const float* fw     = (const float*)d_in[9];
    float* out = (float*)d_out;

    char* ws = (char*)d_ws;
    unsigned short* hid_bf  = (unsigned short*)(ws + 0);          // 83,886,080 B (reused as fused)
    unsigned short* Qb      = (unsigned short*)(ws + 83886080);   // 83,886,080 B
    unsigned short* encp    = (unsigned short*)(ws + 167772160);  // 6,553,600 B
    unsigned short* wq_bt   = (unsigned short*)(ws + 174325760);  // 819,200 B
    unsigned short* wout_bt = (unsigned short*)(ws + 175144960);  // 819,200 B
    unsigned short* wkv_bt  = (unsigned short*)(ws + 175964160);  // 6,553,600 B
    unsigned short* Kg2     = (unsigned short*)(ws + 182517760);  // 3,276,800 B (old kvout slot)
    unsigned short* Vt2     = (unsigned short*)(ws + 185794560);  // 3,276,800 B
    unsigned short* fused   = hid_bf;  // overlays hid_bf (dead after Q GEMM)

    k_cvt_hidden<<<dim3(2048), dim3(256), 0, stream>>>(hidden, hid_bf, 41943040L);
    k_prep<<<dim3(1024), dim3(256), 0, stream>>>(enc, qual, Wq, Wout, Wks, Wvs, Wkq, Wvq,
                                                 encp, wq_bt, wout_bt, wkv_bt);
    hipMemsetAsync(Kg2, 0, 6553600, stream);   // zero K/V padding (l >= 77)
    gemm_kv<<<dim3(20, 10, 2), dim3(256), 0, stream>>>(encp, wkv_bt, Kg2, Vt2);
    gemm_bt<0, 1><<<dim3(2560), dim3(256), 0, stream>>>(hid_bf, wq_bt, (void*)Qb, 640, 640, 0L, 0L, 0L);
    attn_kernel<<<dim3(8, 8, 16), dim3(512), 0, stream>>>(Qb, Kg2, Vt2, fw, fused);
    gemm_bt<1, 1><<<dim3(2560), dim3(256), 0, stream>>>(fused, wout_bt, (void*)out, 640, 640, 0L, 0L, 0L);
}

// Round 16
// 317.767 us; speedup vs baseline: 1.6086x; 1.2678x over previous
//
#include <hip/hip_runtime.h>

using f32x4  = __attribute__((ext_vector_type(4))) float;
using bf16x8 = __attribute__((ext_vector_type(8))) __bf16;

#define AS1(p) ((__attribute__((address_space(1))) void*)(p))
#define AS3(p) ((__attribute__((address_space(3))) void*)(p))

__device__ __forceinline__ unsigned short f2bf(float f) {
    unsigned u = __float_as_uint(f);
    unsigned r = u + 0x7FFFu + ((u >> 16) & 1u);
    return (unsigned short)(r >> 16);
}

__device__ __forceinline__ unsigned cvtpk(float lo, float hi) {
    unsigned r;
    asm("v_cvt_pk_bf16_f32 %0, %1, %2" : "=v"(r) : "v"(lo), "v"(hi));
    return r;
}

__device__ __forceinline__ f32x4 mfma16(bf16x8 a, bf16x8 b, f32x4 c) {
    return __builtin_amdgcn_mfma_f32_16x16x32_bf16(a, b, c, 0, 0, 0);
}

// ---------------- merged prep: hidden cvt + enc pad/cvt + weight transposes ----------------
__global__ void k_prep_all(const float* __restrict__ hidden, unsigned short* __restrict__ hid_bf,
                           const float* __restrict__ enc, const float* __restrict__ qual,
                           const float* __restrict__ Wq, const float* __restrict__ Wout,
                           const float* __restrict__ Wks, const float* __restrict__ Wvs,
                           const float* __restrict__ Wkq, const float* __restrict__ Wvq,
                           unsigned short* __restrict__ encp,
                           unsigned short* __restrict__ wq_bt, unsigned short* __restrict__ wout_bt,
                           unsigned short* __restrict__ wkv_bt) {
    const float scale = 0.11180339887498949f; // 80^-0.5
    const long N_HID = 5242880;               // 41,943,040 / 8
    const long N_ENC = 819200;                // x4 elems
    const long total = N_HID + N_ENC + 4096000;
    long i0 = (long)blockIdx.x * 256 + threadIdx.x;
    long stride = (long)gridDim.x * 256;
    for (long i = i0; i < total; i += stride) {
        if (i < N_HID) {
            long e = i * 8;
            float4 a = *(const float4*)&hidden[e];
            float4 b = *(const float4*)&hidden[e + 4];
            uint4 v;
            v.x = cvtpk(a.x, a.y);
            v.y = cvtpk(a.z, a.w);
            v.z = cvtpk(b.x, b.y);
            v.w = cvtpk(b.z, b.w);
            *(uint4*)&hid_bf[e] = v;
        } else if (i < N_HID + N_ENC) {
            long e = (i - N_HID) * 4;
            int g = (int)(e / (1280L * 1280));
            long rem = e - (long)g * 1280 * 1280;
            int m = (int)(rem / 1280);
            uint2 v = {0u, 0u};
            if (m < 1232) {
                const float* src = (g ? qual : enc) + rem;
                float4 a = *(const float4*)src;
                v.x = f2bf(a.x) | ((unsigned)f2bf(a.y) << 16);
                v.y = f2bf(a.z) | ((unsigned)f2bf(a.w) << 16);
            }
            *(uint2*)&encp[e] = v;
        } else {
            long w = i - N_HID - N_ENC;
            if (w < 409600) {
                int n = (int)(w / 640), k = (int)(w % 640);
                wq_bt[w] = f2bf(Wq[(size_t)k * 640 + n] * scale);
            } else if (w < 819200) {
                long j = w - 409600;
                int n = (int)(j / 640), k = (int)(j % 640);
                wout_bt[j] = f2bf(Wout[(size_t)k * 640 + n]);
            } else {
                long j = w - 819200;
                int g = (int)(j / (1280L * 1280));
                long r = j - (long)g * 1280 * 1280;
                int n = (int)(r / 1280), k = (int)(r % 1280);
                const float* Wk = g ? Wkq : Wks;
                const float* Wv = g ? Wvq : Wvs;
                float val = (n < 640) ? Wk[(size_t)k * 640 + n] : Wv[(size_t)k * 640 + (n - 640)];
                wkv_bt[j] = f2bf(val);
            }
        }
    }
}

// ---------------- GEMM: BK=64, single-buffer 2-barrier, XOR-swizzled LDS ----------------

template <int OUT_F32, int SWZ>
__global__ __launch_bounds__(256) void gemm_bt(
    const unsigned short* __restrict__ A, const unsigned short* __restrict__ Bt,
    void* __restrict__ Cv, int K, int N, long zA, long zB, long zC)
{
    size_t m0; int n0;
    if (SWZ) {
        int i = blockIdx.x;
        int L = (i & 7) * 320 + (i >> 3);   // 2560 blocks, 8 XCDs, 320 per XCD
        n0 = (L % 5) * 128;
        m0 = (size_t)(L / 5) * 128;
    } else {
        m0 = (size_t)blockIdx.x * 128;
        n0 = blockIdx.y * 128;
    }
    const unsigned short* Ab = A + (size_t)blockIdx.z * zA;
    const unsigned short* Bb = Bt + (size_t)blockIdx.z * zB;
    __shared__ __attribute__((aligned(16))) unsigned short As[128 * 64];
    __shared__ __attribute__((aligned(16))) unsigned short Bs[128 * 64];
    const int tid = threadIdx.x, lane = tid & 63, wv = tid >> 6;
    const int wm = wv >> 1, wn = wv & 1;
    const int srow = lane >> 3;
    const int scol = ((lane & 7) ^ srow) * 8;
    f32x4 acc[4][4] = {};
    for (int k0 = 0; k0 < K; k0 += 64) {
        for (int c = wv; c < 16; c += 4) {
            __builtin_amdgcn_global_load_lds(AS1(Ab + (m0 + c * 8 + srow) * K + k0 + scol),
                                             AS3(&As[c * 512]), 16, 0, 0);
            __builtin_amdgcn_global_load_lds(AS1(Bb + ((size_t)(n0 + c * 8 + srow)) * K + k0 + scol),
                                             AS3(&Bs[c * 512]), 16, 0, 0);
        }
        asm volatile("s_waitcnt vmcnt(0)" ::: "memory");
        __syncthreads();
        const int q = lane >> 4, l15 = lane & 15;
#pragma unroll
        for (int kk = 0; kk < 2; ++kk) {
            bf16x8 a[4], b[4];
#pragma unroll
            for (int i = 0; i < 4; ++i) {
                int ra = wm * 64 + i * 16 + l15;
                int rb = wn * 64 + i * 16 + l15;
                a[i] = *(const bf16x8*)&As[ra * 64 + (((kk * 4 + q) ^ (ra & 7)) * 8)];
                b[i] = *(const bf16x8*)&Bs[rb * 64 + (((kk * 4 + q) ^ (rb & 7)) * 8)];
            }
#pragma unroll
            for (int mi = 0; mi < 4; ++mi)
#pragma unroll
                for (int ni = 0; ni < 4; ++ni)
                    acc[mi][ni] = mfma16(a[mi], b[ni], acc[mi][ni]);
        }
        __syncthreads();
    }
#pragma unroll
    for (int mi = 0; mi < 4; ++mi) {
#pragma unroll
        for (int ni = 0; ni < 4; ++ni) {
            size_t row = m0 + wm * 64 + mi * 16 + ((lane >> 4) * 4);
            int col = n0 + wn * 64 + ni * 16 + (lane & 15);
#pragma unroll
            for (int i = 0; i < 4; ++i) {
                float v = acc[mi][ni][i];
                if (OUT_F32)
                    ((float*)Cv + (size_t)blockIdx.z * zC)[(row + i) * N + col] = v;
                else
                    ((unsigned short*)Cv + (size_t)blockIdx.z * zC)[(row + i) * N + col] = f2bf(v);
            }
        }
    }
}

// ---------------- KV GEMM 64x128 with fused scatter epilogue ----------------
__global__ __launch_bounds__(256) void gemm_kv(
    const unsigned short* __restrict__ A, const unsigned short* __restrict__ Bt,
    unsigned short* __restrict__ Kg2, unsigned short* __restrict__ Vt2)
{
    const size_t m0 = (size_t)blockIdx.x * 64;
    const int n0 = blockIdx.y * 128;
    const int g = blockIdx.z;
    const unsigned short* Ab = A + (size_t)g * 1638400;
    const unsigned short* Bb = Bt + (size_t)g * 1638400;
    __shared__ __attribute__((aligned(16))) unsigned short As[64 * 32];
    __shared__ __attribute__((aligned(16))) unsigned short Bs[128 * 32];
    const int tid = threadIdx.x, lane = tid & 63, wv = tid >> 6;
    const int srow = lane >> 2;
    const int scol = ((lane & 3) ^ (srow & 3)) * 8;
    f32x4 acc[4][2] = {};
    for (int k0 = 0; k0 < 1280; k0 += 32) {
        {
            int c = wv;
            __builtin_amdgcn_global_load_lds(AS1(Ab + (m0 + c * 16 + srow) * 1280 + k0 + scol),
                                             AS3(&As[c * 512]), 16, 0, 0);
        }
        for (int c = wv; c < 8; c += 4)
            __builtin_amdgcn_global_load_lds(AS1(Bb + ((size_t)(n0 + c * 16 + srow)) * 1280 + k0 + scol),
                                             AS3(&Bs[c * 512]), 16, 0, 0);
        asm volatile("s_waitcnt vmcnt(0)" ::: "memory");
        __syncthreads();
        const int q = lane >> 4, l15 = lane & 15;
        bf16x8 a[4], b[2];
#pragma unroll
        for (int i = 0; i < 4; ++i) {
            int ra = i * 16 + l15;
            a[i] = *(const bf16x8*)&As[ra * 32 + ((q ^ (ra & 3)) * 8)];
        }
#pragma unroll
        for (int j = 0; j < 2; ++j) {
            int rb = wv * 32 + j * 16 + l15;
            b[j] = *(const bf16x8*)&Bs[rb * 32 + ((q ^ (rb & 3)) * 8)];
        }
#pragma unroll
        for (int mi = 0; mi < 4; ++mi)
#pragma unroll
            for (int ni = 0; ni < 2; ++ni)
                acc[mi][ni] = mfma16(a[mi], b[ni], acc[mi][ni]);
        __syncthreads();
    }
#pragma unroll
    for (int mi = 0; mi < 4; ++mi) {
#pragma unroll
        for (int ni = 0; ni < 2; ++ni) {
            int col = n0 + wv * 32 + ni * 16 + (lane & 15);
#pragma unroll
            for (int i = 0; i < 4; ++i) {
                int row = (int)m0 + mi * 16 + ((lane >> 4) * 4) + i;
                if (row < 1232) {
                    int b = row / 77, l = row - b * 77;
                    unsigned short val = f2bf(acc[mi][ni][i]);
                    if (col < 640) {
                        int h = col / 80, d = col - h * 80;
                        Kg2[(((size_t)g * 16 + b) * 8 + h) * 6400 + l * 80 + d] = val;
                    } else {
                        int c2 = col - 640;
                        int h = c2 / 80, d = c2 - h * 80;
                        Vt2[(((size_t)g * 16 + b) * 8 + h) * 6400 + d * 80 + l] = val;
                    }
                }
            }
        }
    }
}

// ---------------- fused dual attention: software-pipelined S-cluster lookahead ----------------
// grid (8 st, 8 h, 16 b) = 1024 blocks, 512 threads. Each wave: 64 query rows (4 rg x 16).
// 8-stage pipeline over (rg, g): issue S-MFMA(stage n+1), then softmax/pack/PV(stage n).
__global__ __launch_bounds__(512, 4) void attn_kernel(
    const unsigned short* __restrict__ Q,    // [16][4096][640] bf16 (pre-scaled via Wq)
    const unsigned short* __restrict__ Kg2,  // [2][16][8][80][80]
    const unsigned short* __restrict__ Vt2,  // [2][16][8][80][80]
    const float* __restrict__ fw,            // [2]
    unsigned short* __restrict__ fused)      // [16][4096][640] bf16
{
    const int b = blockIdx.z, h = blockIdx.y;
    const int s0 = blockIdx.x * 512;
    __shared__ __attribute__((aligned(16))) unsigned short lds[25600 + 8 * 1408];
    const int tid = threadIdx.x, lane = tid & 63, wv = tid >> 6;
    const int l15 = lane & 15, q = lane >> 4;

    // ---- stage K/V (4 slabs x 800 chunks of 16B), LDS linear
    {
        const unsigned short* sK0 = Kg2 + (size_t)(b * 8 + h) * 6400;
        const unsigned short* sK1 = Kg2 + (size_t)((16 + b) * 8 + h) * 6400;
        const unsigned short* sV0 = Vt2 + (size_t)(b * 8 + h) * 6400;
        const unsigned short* sV1 = Vt2 + (size_t)((16 + b) * 8 + h) * 6400;
#pragma unroll
        for (int it = 0; it < 7; ++it) {
            int chunk = it * 512 + tid;
            if (chunk < 3200) {
                const unsigned short* src = sK0 + (size_t)chunk * 8;
                if (chunk >= 800)  src = sK1 + (size_t)(chunk - 800) * 8;
                if (chunk >= 1600) src = sV0 + (size_t)(chunk - 1600) * 8;
                if (chunk >= 2400) src = sV1 + (size_t)(chunk - 2400) * 8;
                __builtin_amdgcn_global_load_lds(AS1(src), AS3(&lds[(it * 512 + wv * 64) * 8]),
                                                 16, 0, 0);
            }
        }
    }
    asm volatile("s_waitcnt vmcnt(0)" ::: "memory");
    __syncthreads();

    float f0 = fw[0], f1 = fw[1];
    float fm = fmaxf(f0, f1);
    float e0 = __expf(f0 - fm), e1 = __expf(f1 - fm);
    float w0 = e0 / (e0 + e1), w1 = e1 / (e0 + e1);

    unsigned short* obuf = &lds[25600 + wv * 1408];   // per-wave [16][88]

    bf16x8 aq[3];
    f32x4 sA[5], sB[5], o[5];
#pragma unroll
    for (int t = 0; t < 5; ++t) o[t] = f32x4{};

#define AQ_LOAD(RG)                                                                          \
    {                                                                                        \
        const unsigned short* qrow =                                                         \
            Q + ((size_t)b * 4096 + s0 + wv * 64 + (RG) * 16 + l15) * 640 + h * 80;          \
        aq[0] = *(const bf16x8*)(qrow + q * 8);                                              \
        aq[1] = *(const bf16x8*)(qrow + 32 + q * 8);                                         \
        if (q < 2) aq[2] = *(const bf16x8*)(qrow + 64 + q * 8);                              \
        else       aq[2] = bf16x8{};                                                         \
    }

#define SC(G, S)                                                                             \
    {                                                                                        \
        const unsigned short* Ks = &lds[(G) * 6400];                                         \
        _Pragma("unroll") for (int t = 0; t < 5; ++t) S[t] = f32x4{};                        \
        __builtin_amdgcn_s_setprio(1);                                                       \
        _Pragma("unroll") for (int t = 0; t < 5; ++t)                                        \
            _Pragma("unroll") for (int kk = 0; kk < 3; ++kk) {                               \
                bf16x8 ak;                                                                   \
                if (kk < 2 || q < 2)                                                         \
                    ak = *(const bf16x8*)&Ks[(t * 16 + l15) * 80 + kk * 32 + q * 8];         \
                else ak = bf16x8{};                                                          \
                S[t] = mfma16(ak, aq[kk], S[t]);                                             \
            }                                                                                \
        __builtin_amdgcn_s_setprio(0);                                                       \
    }

#define PROC(G, S)                                                                           \
    {                                                                                        \
        float sum = 0.f;                                                                     \
        _Pragma("unroll") for (int t = 0; t < 4; ++t)                                        \
            _Pragma("unroll") for (int i = 0; i < 4; ++i) {                                  \
                S[t][i] = __expf(S[t][i]); sum += S[t][i];                                   \
            }                                                                                \
        _Pragma("unroll") for (int i = 0; i < 4; ++i) {                                      \
            S[4][i] = (q * 4 + i < 13) ? __expf(S[4][i]) : 0.f;                              \
            sum += S[4][i];                                                                  \
        }                                                                                    \
        sum += __shfl_xor(sum, 16);                                                          \
        sum += __shfl_xor(sum, 32);                                                          \
        float rw = ((G) ? w1 : w0) / sum;                                                    \
        uint2 myq[5];                                                                        \
        _Pragma("unroll") for (int t = 0; t < 5; ++t) {                                      \
            myq[t].x = cvtpk(S[t][0] * rw, S[t][1] * rw);                                    \
            myq[t].y = cvtpk(S[t][2] * rw, S[t][3] * rw);                                    \
        }                                                                                    \
        uint4 A[6];                                                                          \
        _Pragma("unroll") for (int t = 0; t < 5; ++t) {                                      \
            unsigned px = __shfl_xor((int)myq[t].x, 16);                                     \
            unsigned py = __shfl_xor((int)myq[t].y, 16);                                     \
            if (q & 1) A[t] = uint4{px, py, myq[t].x, myq[t].y};                             \
            else       A[t] = uint4{myq[t].x, myq[t].y, px, py};                             \
        }                                                                                    \
        A[5] = uint4{0u, 0u, 0u, 0u};                                                        \
        const unsigned short* Vs = &lds[12800 + (G) * 6400];                                 \
        _Pragma("unroll") for (int kk = 0; kk < 3; ++kk) {                                   \
            uint4 own = (q >> 1) ? A[2 * kk + 1] : A[2 * kk];                                \
            uint4 snd = (q >> 1) ? A[2 * kk] : A[2 * kk + 1];                                \
            uint4 rcv;                                                                       \
            rcv.x = __shfl_xor((int)snd.x, 32);                                              \
            rcv.y = __shfl_xor((int)snd.y, 32);                                              \
            rcv.z = __shfl_xor((int)snd.z, 32);                                              \
            rcv.w = __shfl_xor((int)snd.w, 32);                                              \
            uint4 fr = (q == 1 || q == 2) ? rcv : own;                                       \
            bf16x8 pa = __builtin_bit_cast(bf16x8, fr);                                      \
            __builtin_amdgcn_s_setprio(1);                                                   \
            _Pragma("unroll") for (int t = 0; t < 5; ++t) {                                  \
                bf16x8 bv;                                                                   \
                if (kk < 2 || q < 2)                                                         \
                    bv = *(const bf16x8*)&Vs[(t * 16 + l15) * 80 + kk * 32 + q * 8];         \
                else bv = bf16x8{};                                                          \
                o[t] = mfma16(pa, bv, o[t]);                                                 \
            }                                                                                \
            __builtin_amdgcn_s_setprio(0);                                                   \
        }                                                                                    \
    }

#define STORE_O(RG)                                                                          \
    {                                                                                        \
        _Pragma("unroll") for (int t = 0; t < 5; ++t)                                        \
            _Pragma("unroll") for (int i = 0; i < 4; ++i)                                    \
                obuf[(q * 4 + i) * 88 + t * 16 + l15] = f2bf(o[t][i]);                       \
        asm volatile("s_waitcnt lgkmcnt(0)" ::: "memory");                                   \
        const size_t gbase =                                                                 \
            ((size_t)b * 4096 + s0 + wv * 64 + (RG) * 16) * 640 + h * 80;                    \
        _Pragma("unroll") for (int it = 0; it < 3; ++it) {                                   \
            int c = it * 64 + lane;                                                          \
            if (c < 160) {                                                                   \
                int r = c / 10, c10 = c % 10;                                                \
                *(uint4*)(fused + gbase + (size_t)r * 640 + c10 * 8) =                       \
                    *(const uint4*)&obuf[r * 88 + c10 * 8];                                  \
            }                                                                                \
        }                                                                                    \
        _Pragma("unroll") for (int t = 0; t < 5; ++t) o[t] = f32x4{};                        \
    }

    // ---- 8-stage pipeline over (rg, g): S(next) issued before PROC(cur)
    AQ_LOAD(0);
    SC(0, sA);                      // S(rg0,g0)
    SC(1, sB);  PROC(0, sA);        // stage (0,0)
    AQ_LOAD(1);
    SC(0, sA);  PROC(1, sB);  STORE_O(0);   // stage (0,1)
    SC(1, sB);  PROC(0, sA);        // stage (1,0)
    AQ_LOAD(2);
    SC(0, sA);  PROC(1, sB);  STORE_O(1);   // stage (1,1)
    SC(1, sB);  PROC(0, sA);        // stage (2,0)
    AQ_LOAD(3);
    SC(0, sA);  PROC(1, sB);  STORE_O(2);   // stage (2,1)
    SC(1, sB);  PROC(0, sA);        // stage (3,0)
    PROC(1, sB);  STORE_O(3);       // stage (3,1) — nothing left to issue

#undef AQ_LOAD
#undef SC
#undef PROC
#undef STORE_O
}

// ---------------- launcher ----------------

extern "C" void kernel_launch(void* const* d_in, const int* in_sizes, int n_in,
                              void* d_out, int out_size, void* d_ws, size_t ws_size,
                              hipStream_t stream) {
    const float* hidden = (const float*)d_in[0];
    const float* enc    = (const float*)d_in[1];
    const float* qual   = (const float*)d_in[2];
    const float* Wq     = (const float*)d_in[3];
    const float* Wks    = (const float*)d_in[4];
    const float* Wvs    = (const float*)d_in[5];
    const float* Wkq    = (const float*)d_in[6];
    const float* Wvq    = (const float*)d_in[7];
    const float* Wout   = (const float*)d_in[8];
    const float* fw     = (const float*)d_in[9];
    float* out = (float*)d_out;

    char* ws = (char*)d_ws;
    unsigned short* hid_bf  = (unsigned short*)(ws + 0);          // 83,886,080 B (reused as fused)
    unsigned short* Qb      = (unsigned short*)(ws + 83886080);   // 83,886,080 B
    unsigned short* encp    = (unsigned short*)(ws + 167772160);  // 6,553,600 B
    unsigned short* wq_bt   = (unsigned short*)(ws + 174325760);  // 819,200 B
    unsigned short* wout_bt = (unsigned short*)(ws + 175144960);  // 819,200 B
    unsigned short* wkv_bt  = (unsigned short*)(ws + 175964160);  // 6,553,600 B
    unsigned short* Kg2     = (unsigned short*)(ws + 182517760);  // 3,276,800 B
    unsigned short* Vt2     = (unsigned short*)(ws + 185794560);  // 3,276,800 B
    unsigned short* fused   = hid_bf;  // overlays hid_bf (dead after Q GEMM)

    k_prep_all<<<dim3(2048), dim3(256), 0, stream>>>(hidden, hid_bf, enc, qual,
                                                     Wq, Wout, Wks, Wvs, Wkq, Wvq,
                                                     encp, wq_bt, wout_bt, wkv_bt);
    hipMemsetAsync(Kg2, 0, 6553600, stream);   // zero K/V padding (l >= 77)
    gemm_kv<<<dim3(20, 10, 2), dim3(256), 0, stream>>>(encp, wkv_bt, Kg2, Vt2);
    gemm_bt<0, 1><<<dim3(2560), dim3(256), 0, stream>>>(hid_bf, wq_bt, (void*)Qb, 640, 640, 0L, 0L, 0L);
    attn_kernel<<<dim3(8, 8, 16), dim3(512), 0, stream>>>(Qb, Kg2, Vt2, fw, fused);
    gemm_bt<1, 1><<<dim3(2560), dim3(256), 0, stream>>>(fused, wout_bt, (void*)out, 640, 640, 0L, 0L, 0L);
}

// Round 17
// 297.941 us; speedup vs baseline: 1.7157x; 1.0665x over previous
//
#include <hip/hip_runtime.h>

using f32x4  = __attribute__((ext_vector_type(4))) float;
using bf16x8 = __attribute__((ext_vector_type(8))) __bf16;

#define AS1(p) ((__attribute__((address_space(1))) void*)(p))
#define AS3(p) ((__attribute__((address_space(3))) void*)(p))

__device__ __forceinline__ unsigned short f2bf(float f) {
    unsigned u = __float_as_uint(f);
    unsigned r = u + 0x7FFFu + ((u >> 16) & 1u);
    return (unsigned short)(r >> 16);
}

__device__ __forceinline__ unsigned cvtpk(float lo, float hi) {
    unsigned r;
    asm("v_cvt_pk_bf16_f32 %0, %1, %2" : "=v"(r) : "v"(lo), "v"(hi));
    return r;
}

__device__ __forceinline__ f32x4 mfma16(bf16x8 a, bf16x8 b, f32x4 c) {
    return __builtin_amdgcn_mfma_f32_16x16x32_bf16(a, b, c, 0, 0, 0);
}

// ---------------- streaming prep: hidden f32->bf16 + enc pad/cvt (fully coalesced) ----------------
__global__ void k_stream(const float* __restrict__ hidden, unsigned short* __restrict__ hid_bf,
                         const float* __restrict__ enc, const float* __restrict__ qual,
                         unsigned short* __restrict__ encp) {
    const long N_HID = 5242880;               // 41,943,040 / 8
    const long N_ENC = 819200;                // x4 elems
    const long total = N_HID + N_ENC;
    long i0 = (long)blockIdx.x * 256 + threadIdx.x;
    long stride = (long)gridDim.x * 256;
    for (long i = i0; i < total; i += stride) {
        if (i < N_HID) {
            long e = i * 8;
            float4 a = *(const float4*)&hidden[e];
            float4 b = *(const float4*)&hidden[e + 4];
            uint4 v;
            v.x = cvtpk(a.x, a.y);
            v.y = cvtpk(a.z, a.w);
            v.z = cvtpk(b.x, b.y);
            v.w = cvtpk(b.z, b.w);
            *(uint4*)&hid_bf[e] = v;
        } else {
            long e = (i - N_HID) * 4;
            int g = (int)(e / (1280L * 1280));
            long rem = e - (long)g * 1280 * 1280;
            int m = (int)(rem / 1280);
            uint2 v = {0u, 0u};
            if (m < 1232) {
                const float* src = (g ? qual : enc) + rem;
                float4 a = *(const float4*)src;
                v.x = f2bf(a.x) | ((unsigned)f2bf(a.y) << 16);
                v.y = f2bf(a.z) | ((unsigned)f2bf(a.w) << 16);
            }
            *(uint2*)&encp[e] = v;
        }
    }
}

// ---------------- LDS-tile weight transpose: coalesced reads AND writes ----------------
// z: 0 Wq->wq_bt (*scale), 1 Wout->wout_bt, 2 Wks->wkv0[n<640], 3 Wvs->wkv0[n>=640],
//    4 Wkq->wkv1[n<640], 5 Wvq->wkv1[n>=640].  src f32 [K][640]; dst bf16 [.][K].
__global__ __launch_bounds__(256) void k_transpose_w(
    const float* __restrict__ Wq, const float* __restrict__ Wout,
    const float* __restrict__ Wks, const float* __restrict__ Wvs,
    const float* __restrict__ Wkq, const float* __restrict__ Wvq,
    unsigned short* __restrict__ wq_bt, unsigned short* __restrict__ wout_bt,
    unsigned short* __restrict__ wkv_bt) {
    const int z = blockIdx.z;
    const float* src; unsigned short* dst; int K; int nbase; float scale = 1.0f;
    switch (z) {
        case 0:  src = Wq;  dst = wq_bt;             K = 640;  nbase = 0;
                 scale = 0.11180339887498949f; break;
        case 1:  src = Wout; dst = wout_bt;          K = 640;  nbase = 0;   break;
        case 2:  src = Wks; dst = wkv_bt;            K = 1280; nbase = 0;   break;
        case 3:  src = Wvs; dst = wkv_bt;            K = 1280; nbase = 640; break;
        case 4:  src = Wkq; dst = wkv_bt + 1638400;  K = 1280; nbase = 0;   break;
        default: src = Wvq; dst = wkv_bt + 1638400;  K = 1280; nbase = 640; break;
    }
    const int k0 = blockIdx.x * 64;
    if (k0 >= K) return;
    const int n0 = blockIdx.y * 64;
    __shared__ float t[64][65];
    const int r4 = threadIdx.x >> 6, c = threadIdx.x & 63;
#pragma unroll
    for (int it = 0; it < 16; ++it) {
        int r = r4 + 4 * it;
        t[r][c] = src[(size_t)(k0 + r) * 640 + n0 + c];   // coalesced 256B rows
    }
    __syncthreads();
#pragma unroll
    for (int it = 0; it < 16; ++it) {
        int n = r4 + 4 * it;
        dst[(size_t)(nbase + n0 + n) * K + k0 + c] = f2bf(t[c][n] * scale);  // coalesced 128B rows
    }
}

// ---------------- GEMM: BK=64, single-buffer 2-barrier, XOR-swizzled LDS ----------------

template <int OUT_F32, int SWZ>
__global__ __launch_bounds__(256) void gemm_bt(
    const unsigned short* __restrict__ A, const unsigned short* __restrict__ Bt,
    void* __restrict__ Cv, int K, int N, long zA, long zB, long zC)
{
    size_t m0; int n0;
    if (SWZ) {
        int i = blockIdx.x;
        int L = (i & 7) * 320 + (i >> 3);   // 2560 blocks, 8 XCDs, 320 per XCD
        n0 = (L % 5) * 128;
        m0 = (size_t)(L / 5) * 128;
    } else {
        m0 = (size_t)blockIdx.x * 128;
        n0 = blockIdx.y * 128;
    }
    const unsigned short* Ab = A + (size_t)blockIdx.z * zA;
    const unsigned short* Bb = Bt + (size_t)blockIdx.z * zB;
    __shared__ __attribute__((aligned(16))) unsigned short As[128 * 64];
    __shared__ __attribute__((aligned(16))) unsigned short Bs[128 * 64];
    const int tid = threadIdx.x, lane = tid & 63, wv = tid >> 6;
    const int wm = wv >> 1, wn = wv & 1;
    const int srow = lane >> 3;
    const int scol = ((lane & 7) ^ srow) * 8;
    f32x4 acc[4][4] = {};
    for (int k0 = 0; k0 < K; k0 += 64) {
        for (int c = wv; c < 16; c += 4) {
            __builtin_amdgcn_global_load_lds(AS1(Ab + (m0 + c * 8 + srow) * K + k0 + scol),
                                             AS3(&As[c * 512]), 16, 0, 0);
            __builtin_amdgcn_global_load_lds(AS1(Bb + ((size_t)(n0 + c * 8 + srow)) * K + k0 + scol),
                                             AS3(&Bs[c * 512]), 16, 0, 0);
        }
        asm volatile("s_waitcnt vmcnt(0)" ::: "memory");
        __syncthreads();
        const int q = lane >> 4, l15 = lane & 15;
#pragma unroll
        for (int kk = 0; kk < 2; ++kk) {
            bf16x8 a[4], b[4];
#pragma unroll
            for (int i = 0; i < 4; ++i) {
                int ra = wm * 64 + i * 16 + l15;
                int rb = wn * 64 + i * 16 + l15;
                a[i] = *(const bf16x8*)&As[ra * 64 + (((kk * 4 + q) ^ (ra & 7)) * 8)];
                b[i] = *(const bf16x8*)&Bs[rb * 64 + (((kk * 4 + q) ^ (rb & 7)) * 8)];
            }
#pragma unroll
            for (int mi = 0; mi < 4; ++mi)
#pragma unroll
                for (int ni = 0; ni < 4; ++ni)
                    acc[mi][ni] = mfma16(a[mi], b[ni], acc[mi][ni]);
        }
        __syncthreads();
    }
#pragma unroll
    for (int mi = 0; mi < 4; ++mi) {
#pragma unroll
        for (int ni = 0; ni < 4; ++ni) {
            size_t row = m0 + wm * 64 + mi * 16 + ((lane >> 4) * 4);
            int col = n0 + wn * 64 + ni * 16 + (lane & 15);
#pragma unroll
            for (int i = 0; i < 4; ++i) {
                float v = acc[mi][ni][i];
                if (OUT_F32)
                    ((float*)Cv + (size_t)blockIdx.z * zC)[(row + i) * N + col] = v;
                else
                    ((unsigned short*)Cv + (size_t)blockIdx.z * zC)[(row + i) * N + col] = f2bf(v);
            }
        }
    }
}

// ---------------- KV GEMM 64x128 with fused scatter epilogue ----------------
__global__ __launch_bounds__(256) void gemm_kv(
    const unsigned short* __restrict__ A, const unsigned short* __restrict__ Bt,
    unsigned short* __restrict__ Kg2, unsigned short* __restrict__ Vt2)
{
    const size_t m0 = (size_t)blockIdx.x * 64;
    const int n0 = blockIdx.y * 128;
    const int g = blockIdx.z;
    const unsigned short* Ab = A + (size_t)g * 1638400;
    const unsigned short* Bb = Bt + (size_t)g * 1638400;
    __shared__ __attribute__((aligned(16))) unsigned short As[64 * 32];
    __shared__ __attribute__((aligned(16))) unsigned short Bs[128 * 32];
    const int tid = threadIdx.x, lane = tid & 63, wv = tid >> 6;
    const int srow = lane >> 2;
    const int scol = ((lane & 3) ^ (srow & 3)) * 8;
    f32x4 acc[4][2] = {};
    for (int k0 = 0; k0 < 1280; k0 += 32) {
        {
            int c = wv;
            __builtin_amdgcn_global_load_lds(AS1(Ab + (m0 + c * 16 + srow) * 1280 + k0 + scol),
                                             AS3(&As[c * 512]), 16, 0, 0);
        }
        for (int c = wv; c < 8; c += 4)
            __builtin_amdgcn_global_load_lds(AS1(Bb + ((size_t)(n0 + c * 16 + srow)) * 1280 + k0 + scol),
                                             AS3(&Bs[c * 512]), 16, 0, 0);
        asm volatile("s_waitcnt vmcnt(0)" ::: "memory");
        __syncthreads();
        const int q = lane >> 4, l15 = lane & 15;
        bf16x8 a[4], b[2];
#pragma unroll
        for (int i = 0; i < 4; ++i) {
            int ra = i * 16 + l15;
            a[i] = *(const bf16x8*)&As[ra * 32 + ((q ^ (ra & 3)) * 8)];
        }
#pragma unroll
        for (int j = 0; j < 2; ++j) {
            int rb = wv * 32 + j * 16 + l15;
            b[j] = *(const bf16x8*)&Bs[rb * 32 + ((q ^ (rb & 3)) * 8)];
        }
#pragma unroll
        for (int mi = 0; mi < 4; ++mi)
#pragma unroll
            for (int ni = 0; ni < 2; ++ni)
                acc[mi][ni] = mfma16(a[mi], b[ni], acc[mi][ni]);
        __syncthreads();
    }
#pragma unroll
    for (int mi = 0; mi < 4; ++mi) {
#pragma unroll
        for (int ni = 0; ni < 2; ++ni) {
            int col = n0 + wv * 32 + ni * 16 + (lane & 15);
#pragma unroll
            for (int i = 0; i < 4; ++i) {
                int row = (int)m0 + mi * 16 + ((lane >> 4) * 4) + i;
                if (row < 1232) {
                    int b = row / 77, l = row - b * 77;
                    unsigned short val = f2bf(acc[mi][ni][i]);
                    if (col < 640) {
                        int h = col / 80, d = col - h * 80;
                        Kg2[(((size_t)g * 16 + b) * 8 + h) * 6400 + l * 80 + d] = val;
                    } else {
                        int c2 = col - 640;
                        int h = c2 / 80, d = c2 - h * 80;
                        Vt2[(((size_t)g * 16 + b) * 8 + h) * 6400 + d * 80 + l] = val;
                    }
                }
            }
        }
    }
}

// ---------------- fused dual attention: software-pipelined S-cluster lookahead ----------------
// grid (8 st, 8 h, 16 b) = 1024 blocks, 512 threads. Each wave: 64 query rows (4 rg x 16).
// 8-stage pipeline over (rg, g): issue S-MFMA(stage n+1), then softmax/pack/PV(stage n).
__global__ __launch_bounds__(512, 4) void attn_kernel(
    const unsigned short* __restrict__ Q,    // [16][4096][640] bf16 (pre-scaled via Wq)
    const unsigned short* __restrict__ Kg2,  // [2][16][8][80][80]
    const unsigned short* __restrict__ Vt2,  // [2][16][8][80][80]
    const float* __restrict__ fw,            // [2]
    unsigned short* __restrict__ fused)      // [16][4096][640] bf16
{
    const int b = blockIdx.z, h = blockIdx.y;
    const int s0 = blockIdx.x * 512;
    __shared__ __attribute__((aligned(16))) unsigned short lds[25600 + 8 * 1408];
    const int tid = threadIdx.x, lane = tid & 63, wv = tid >> 6;
    const int l15 = lane & 15, q = lane >> 4;

    // ---- stage K/V (4 slabs x 800 chunks of 16B), LDS linear
    {
        const unsigned short* sK0 = Kg2 + (size_t)(b * 8 + h) * 6400;
        const unsigned short* sK1 = Kg2 + (size_t)((16 + b) * 8 + h) * 6400;
        const unsigned short* sV0 = Vt2 + (size_t)(b * 8 + h) * 6400;
        const unsigned short* sV1 = Vt2 + (size_t)((16 + b) * 8 + h) * 6400;
#pragma unroll
        for (int it = 0; it < 7; ++it) {
            int chunk = it * 512 + tid;
            if (chunk < 3200) {
                const unsigned short* src = sK0 + (size_t)chunk * 8;
                if (chunk >= 800)  src = sK1 + (size_t)(chunk - 800) * 8;
                if (chunk >= 1600) src = sV0 + (size_t)(chunk - 1600) * 8;
                if (chunk >= 2400) src = sV1 + (size_t)(chunk - 2400) * 8;
                __builtin_amdgcn_global_load_lds(AS1(src), AS3(&lds[(it * 512 + wv * 64) * 8]),
                                                 16, 0, 0);
            }
        }
    }
    asm volatile("s_waitcnt vmcnt(0)" ::: "memory");
    __syncthreads();

    float f0 = fw[0], f1 = fw[1];
    float fm = fmaxf(f0, f1);
    float e0 = __expf(f0 - fm), e1 = __expf(f1 - fm);
    float w0 = e0 / (e0 + e1), w1 = e1 / (e0 + e1);

    unsigned short* obuf = &lds[25600 + wv * 1408];   // per-wave [16][88]

    bf16x8 aq[3];
    f32x4 sA[5], sB[5], o[5];
#pragma unroll
    for (int t = 0; t < 5; ++t) o[t] = f32x4{};

#define AQ_LOAD(RG)                                                                          \
    {                                                                                        \
        const unsigned short* qrow =                                                         \
            Q + ((size_t)b * 4096 + s0 + wv * 64 + (RG) * 16 + l15) * 640 + h * 80;          \
        aq[0] = *(const bf16x8*)(qrow + q * 8);                                              \
        aq[1] = *(const bf16x8*)(qrow + 32 + q * 8);                                         \
        if (q < 2) aq[2] = *(const bf16x8*)(qrow + 64 + q * 8);                              \
        else       aq[2] = bf16x8{};                                                         \
    }

#define SC(G, S)                                                                             \
    {                                                                                        \
        const unsigned short* Ks = &lds[(G) * 6400];                                         \
        _Pragma("unroll") for (int t = 0; t < 5; ++t) S[t] = f32x4{};                        \
        __builtin_amdgcn_s_setprio(1);                                                       \
        _Pragma("unroll") for (int t = 0; t < 5; ++t)                                        \
            _Pragma("unroll") for (int kk = 0; kk < 3; ++kk) {                               \
                bf16x8 ak;                                                                   \
                if (kk < 2 || q < 2)                                                         \
                    ak = *(const bf16x8*)&Ks[(t * 16 + l15) * 80 + kk * 32 + q * 8];         \
                else ak = bf16x8{};                                                          \
                S[t] = mfma16(ak, aq[kk], S[t]);                                             \
            }                                                                                \
        __builtin_amdgcn_s_setprio(0);                                                       \
    }

#define PROC(G, S)                                                                           \
    {                                                                                        \
        float sum = 0.f;                                                                     \
        _Pragma("unroll") for (int t = 0; t < 4; ++t)                                        \
            _Pragma("unroll") for (int i = 0; i < 4; ++i) {                                  \
                S[t][i] = __expf(S[t][i]); sum += S[t][i];                                   \
            }                                                                                \
        _Pragma("unroll") for (int i = 0; i < 4; ++i) {                                      \
            S[4][i] = (q * 4 + i < 13) ? __expf(S[4][i]) : 0.f;                              \
            sum += S[4][i];                                                                  \
        }                                                                                    \
        sum += __shfl_xor(sum, 16);                                                          \
        sum += __shfl_xor(sum, 32);                                                          \
        float rw = ((G) ? w1 : w0) / sum;                                                    \
        uint2 myq[5];                                                                        \
        _Pragma("unroll") for (int t = 0; t < 5; ++t) {                                      \
            myq[t].x = cvtpk(S[t][0] * rw, S[t][1] * rw);                                    \
            myq[t].y = cvtpk(S[t][2] * rw, S[t][3] * rw);                                    \
        }                                                                                    \
        uint4 A[6];                                                                          \
        _Pragma("unroll") for (int t = 0; t < 5; ++t) {                                      \
            unsigned px = __shfl_xor((int)myq[t].x, 16);                                     \
            unsigned py = __shfl_xor((int)myq[t].y, 16);                                     \
            if (q & 1) A[t] = uint4{px, py, myq[t].x, myq[t].y};                             \
            else       A[t] = uint4{myq[t].x, myq[t].y, px, py};                             \
        }                                                                                    \
        A[5] = uint4{0u, 0u, 0u, 0u};                                                        \
        const unsigned short* Vs = &lds[12800 + (G) * 6400];                                 \
        _Pragma("unroll") for (int kk = 0; kk < 3; ++kk) {                                   \
            uint4 own = (q >> 1) ? A[2 * kk + 1] : A[2 * kk];                                \
            uint4 snd = (q >> 1) ? A[2 * kk] : A[2 * kk + 1];                                \
            uint4 rcv;                                                                       \
            rcv.x = __shfl_xor((int)snd.x, 32);                                              \
            rcv.y = __shfl_xor((int)snd.y, 32);                                              \
            rcv.z = __shfl_xor((int)snd.z, 32);                                              \
            rcv.w = __shfl_xor((int)snd.w, 32);                                              \
            uint4 fr = (q == 1 || q == 2) ? rcv : own;                                       \
            bf16x8 pa = __builtin_bit_cast(bf16x8, fr);                                      \
            __builtin_amdgcn_s_setprio(1);                                                   \
            _Pragma("unroll") for (int t = 0; t < 5; ++t) {                                  \
                bf16x8 bv;                                                                   \
                if (kk < 2 || q < 2)                                                         \
                    bv = *(const bf16x8*)&Vs[(t * 16 + l15) * 80 + kk * 32 + q * 8];         \
                else bv = bf16x8{};                                                          \
                o[t] = mfma16(pa, bv, o[t]);                                                 \
            }                                                                                \
            __builtin_amdgcn_s_setprio(0);                                                   \
        }                                                                                    \
    }

#define STORE_O(RG)                                                                          \
    {                                                                                        \
        _Pragma("unroll") for (int t = 0; t < 5; ++t)                                        \
            _Pragma("unroll") for (int i = 0; i < 4; ++i)                                    \
                obuf[(q * 4 + i) * 88 + t * 16 + l15] = f2bf(o[t][i]);                       \
        asm volatile("s_waitcnt lgkmcnt(0)" ::: "memory");                                   \
        const size_t gbase =                                                                 \
            ((size_t)b * 4096 + s0 + wv * 64 + (RG) * 16) * 640 + h * 80;                    \
        _Pragma("unroll") for (int it = 0; it < 3; ++it) {                                   \
            int c = it * 64 + lane;                                                          \
            if (c < 160) {                                                                   \
                int r = c / 10, c10 = c % 10;                                                \
                *(uint4*)(fused + gbase + (size_t)r * 640 + c10 * 8) =                       \
                    *(const uint4*)&obuf[r * 88 + c10 * 8];                                  \
            }                                                                                \
        }                                                                                    \
        _Pragma("unroll") for (int t = 0; t < 5; ++t) o[t] = f32x4{};                        \
    }

    // ---- 8-stage pipeline over (rg, g): S(next) issued before PROC(cur)
    AQ_LOAD(0);
    SC(0, sA);                      // S(rg0,g0)
    SC(1, sB);  PROC(0, sA);        // stage (0,0)
    AQ_LOAD(1);
    SC(0, sA);  PROC(1, sB);  STORE_O(0);   // stage (0,1)
    SC(1, sB);  PROC(0, sA);        // stage (1,0)
    AQ_LOAD(2);
    SC(0, sA);  PROC(1, sB);  STORE_O(1);   // stage (1,1)
    SC(1, sB);  PROC(0, sA);        // stage (2,0)
    AQ_LOAD(3);
    SC(0, sA);  PROC(1, sB);  STORE_O(2);   // stage (2,1)
    SC(1, sB);  PROC(0, sA);        // stage (3,0)
    PROC(1, sB);  STORE_O(3);       // stage (3,1) — nothing left to issue

#undef AQ_LOAD
#undef SC
#undef PROC
#undef STORE_O
}

// ---------------- launcher ----------------

extern "C" void kernel_launch(void* const* d_in, const int* in_sizes, int n_in,
                              void* d_out, int out_size, void* d_ws, size_t ws_size,
                              hipStream_t stream) {
    const float* hidden = (const float*)d_in[0];
    const float* enc    = (const float*)d_in[1];
    const float* qual   = (const float*)d_in[2];
    const float* Wq     = (const float*)d_in[3];
    const float* Wks    = (const float*)d_in[4];
    const float* Wvs    = (const float*)d_in[5];
    const float* Wkq    = (const float*)d_in[6];
    const float* Wvq    = (const float*)d_in[7];
    const float* Wout   = (const float*)d_in[8];
    const float* fw     = (const float*)d_in[9];
    float* out = (float*)d_out;

    char* ws = (char*)d_ws;
    unsigned short* hid_bf  = (unsigned short*)(ws + 0);          // 83,886,080 B (reused as fused)
    unsigned short* Qb      = (unsigned short*)(ws + 83886080);   // 83,886,080 B
    unsigned short* encp    = (unsigned short*)(ws + 167772160);  // 6,553,600 B
    unsigned short* wq_bt   = (unsigned short*)(ws + 174325760);  // 819,200 B
    unsigned short* wout_bt = (unsigned short*)(ws + 175144960);  // 819,200 B
    unsigned short* wkv_bt  = (unsigned short*)(ws + 175964160);  // 6,553,600 B
    unsigned short* Kg2     = (unsigned short*)(ws + 182517760);  // 3,276,800 B
    unsigned short* Vt2     = (unsigned short*)(ws + 185794560);  // 3,276,800 B
    unsigned short* fused   = hid_bf;  // overlays hid_bf (dead after Q GEMM)

    k_stream<<<dim3(2048), dim3(256), 0, stream>>>(hidden, hid_bf, enc, qual, encp);
    k_transpose_w<<<dim3(20, 10, 6), dim3(256), 0, stream>>>(Wq, Wout, Wks, Wvs, Wkq, Wvq,
                                                             wq_bt, wout_bt, wkv_bt);
    hipMemsetAsync(Kg2, 0, 6553600, stream);   // zero K/V padding (l >= 77)
    gemm_kv<<<dim3(20, 10, 2), dim3(256), 0, stream>>>(encp, wkv_bt, Kg2, Vt2);
    gemm_bt<0, 1><<<dim3(2560), dim3(256), 0, stream>>>(hid_bf, wq_bt, (void*)Qb, 640, 640, 0L, 0L, 0L);
    attn_kernel<<<dim3(8, 8, 16), dim3(512), 0, stream>>>(Qb, Kg2, Vt2, fw, fused);
    gemm_bt<1, 1><<<dim3(2560), dim3(256), 0, stream>>>(fused, wout_bt, (void*)out, 640, 640, 0L, 0L, 0L);
}